// Round 9
// baseline (199.356 us; speedup 1.0000x reference)
//
#include <hip/hip_runtime.h>
#include <cstdint>
#include <cstddef>

// GAT 2-layer forward. Bucket bin (64-node buckets) -> exact CSR,
// fused softmax-aggregate (2 nodes/wave) with gemm2 in agg1 epilogue,
// h1 stored FP16 (v_fma_mix path: no unpack instructions in agg1 loop),
// transposed-LDS gemm1. No float atomics, no segment-max pass.

#define NEG_SLOPE 0.2f
#define BIN_CHUNK 4096
#define CAP 2560   // per-bucket slice capacity; mean count ~2112 (9.7 sigma)

typedef _Float16 f16x2 __attribute__((ext_vector_type(2)));

__device__ __forceinline__ float leaky(float v) {
    return v >= 0.f ? v : NEG_SLOPE * v;
}
__device__ __forceinline__ float elu1(float v) {
    return v > 0.f ? v : expm1f(v);
}

// ---------------- K1: bin edges into fixed-capacity bucket slices ----------------
// cursor[] starts zeroed (memset); slice base is b*CAP. Bucket = dst>>6.
__global__ __launch_bounds__(256) void bin_kernel(
    const int* __restrict__ src, const int* __restrict__ dst,
    int* __restrict__ cursor, unsigned* __restrict__ binned,
    int E, int Etot, int NB) {
    __shared__ int hist[800];
    __shared__ int basesh[800];
    for (int i = threadIdx.x; i < NB; i += 256) hist[i] = 0;
    __syncthreads();
    unsigned pk[BIN_CHUNK / 256];
    int base = blockIdx.x * BIN_CHUNK;
#pragma unroll
    for (int k = 0; k < BIN_CHUNK / 256; ++k) {
        int e = base + k * 256 + threadIdx.x;
        pk[k] = 0xFFFFFFFFu;
        if (e < Etot) {
            int s, d;
            if (e < E) { s = src[e]; d = dst[e]; }
            else       { s = d = e - E; }  // self loops appended
            pk[k] = ((unsigned)d << 16) | (unsigned)s;
            atomicAdd(&hist[d >> 6], 1);
        }
    }
    __syncthreads();
    for (int i = threadIdx.x; i < NB; i += 256) {
        int c = hist[i];
        basesh[i] = c ? (i * CAP + atomicAdd(&cursor[i], c)) : 0;
        hist[i] = 0;  // reuse as local cursor
    }
    __syncthreads();
#pragma unroll
    for (int k = 0; k < BIN_CHUNK / 256; ++k) {
        if (pk[k] != 0xFFFFFFFFu) {
            int b = pk[k] >> 22;  // = dst >> 6
            int pos = basesh[b] + atomicAdd(&hist[b], 1);
            binned[pos] = pk[k];
        }
    }
}

// ---------------- K2: per-bucket (64 nodes) exact CSR ----------------
__global__ __launch_bounds__(256) void csr_build_kernel(
    const unsigned* __restrict__ binned, const int* __restrict__ cursor,
    int2* __restrict__ rng, int* __restrict__ csr, int N, int NB) {
    __shared__ int hist[64];
    __shared__ int sc[64];
    __shared__ int cur[64];
    const int b = blockIdx.x;
    const int base = b * CAP;
    const int endp = base + cursor[b];
    const int t = threadIdx.x;
    if (t < 64) hist[t] = 0;
    __syncthreads();
    for (int i = base + t; i < endp; i += 256)
        atomicAdd(&hist[(binned[i] >> 16) & 63], 1);
    __syncthreads();
    int v = (t < 64) ? hist[t] : 0;
    if (t < 64) sc[t] = v;
    __syncthreads();
    for (int off = 1; off < 64; off <<= 1) {
        int u = (t >= off && t < 64) ? sc[t - off] : 0;
        __syncthreads();
        if (t < 64) sc[t] += u;
        __syncthreads();
    }
    if (t < 64) {
        int beg = base + sc[t] - v;
        cur[t] = beg;
        int node = b * 64 + t;
        if (node < N) rng[node] = make_int2(beg, beg + v);
    }
    __syncthreads();
    for (int i = base + t; i < endp; i += 256) {
        unsigned p = binned[i];
        int pos = atomicAdd(&cur[(p >> 16) & 63], 1);
        csr[pos] = (int)(p & 0xFFFFu);
    }
}

// ---------------- Layer 1 GEMM (x @ W1) + scores, fp16 h1 out ----------------
// 64 rows x 64 cols per block; each thread 4 rows x 4 cols.
__global__ __launch_bounds__(256) void gemm1_kernel(
    const float* __restrict__ x, const float* __restrict__ W1,
    const float* __restrict__ a_src, const float* __restrict__ a_dst,
    unsigned short* __restrict__ h1b, float* __restrict__ ssrc1,
    float* __restrict__ sdst1, int N) {
    __shared__ float Ws[128 * 64];
    __shared__ float Xt[128][69];   // pad 69: staging stores spread 8 banks

    const int t = threadIdx.x;
    const int row0 = blockIdx.x * 64;

    for (int i = t * 4; i < 128 * 64; i += 1024) {
        *(float4*)&Ws[i] = *(const float4*)&W1[i];
    }
    for (int i = t * 4; i < 64 * 128; i += 1024) {
        int r = i >> 7, k = i & 127;
        float4 v = make_float4(0.f, 0.f, 0.f, 0.f);
        if (row0 + r < N) v = *(const float4*)&x[(size_t)(row0 + r) * 128 + k];
        Xt[k][r] = v.x; Xt[k + 1][r] = v.y; Xt[k + 2][r] = v.z; Xt[k + 3][r] = v.w;
    }
    __syncthreads();

    const int r0 = (t >> 4) * 4;
    const int c0 = (t & 15) * 4;
    float acc[4][4] = {};
#pragma unroll 4
    for (int k = 0; k < 128; ++k) {
        float4 wv = *(const float4*)&Ws[k * 64 + c0];
        float4 xv = *(const float4*)&Xt[k][r0];
        acc[0][0] = fmaf(xv.x, wv.x, acc[0][0]); acc[0][1] = fmaf(xv.x, wv.y, acc[0][1]);
        acc[0][2] = fmaf(xv.x, wv.z, acc[0][2]); acc[0][3] = fmaf(xv.x, wv.w, acc[0][3]);
        acc[1][0] = fmaf(xv.y, wv.x, acc[1][0]); acc[1][1] = fmaf(xv.y, wv.y, acc[1][1]);
        acc[1][2] = fmaf(xv.y, wv.z, acc[1][2]); acc[1][3] = fmaf(xv.y, wv.w, acc[1][3]);
        acc[2][0] = fmaf(xv.z, wv.x, acc[2][0]); acc[2][1] = fmaf(xv.z, wv.y, acc[2][1]);
        acc[2][2] = fmaf(xv.z, wv.z, acc[2][2]); acc[2][3] = fmaf(xv.z, wv.w, acc[2][3]);
        acc[3][0] = fmaf(xv.w, wv.x, acc[3][0]); acc[3][1] = fmaf(xv.w, wv.y, acc[3][1]);
        acc[3][2] = fmaf(xv.w, wv.z, acc[3][2]); acc[3][3] = fmaf(xv.w, wv.w, acc[3][3]);
    }
    float4 av = *(const float4*)&a_src[c0];
    float4 bv = *(const float4*)&a_dst[c0];
    float ps[4], pd[4];
#pragma unroll
    for (int rr = 0; rr < 4; ++rr) {
        int row = row0 + r0 + rr;
        if (row < N) {
            f16x2 u0 = {(_Float16)acc[rr][0], (_Float16)acc[rr][1]};
            f16x2 u1 = {(_Float16)acc[rr][2], (_Float16)acc[rr][3]};
            uint2 st;
            st.x = __builtin_bit_cast(unsigned, u0);
            st.y = __builtin_bit_cast(unsigned, u1);
            *(uint2*)&h1b[(size_t)row * 64 + c0] = st;
        }
        ps[rr] = acc[rr][0] * av.x + acc[rr][1] * av.y + acc[rr][2] * av.z + acc[rr][3] * av.w;
        pd[rr] = acc[rr][0] * bv.x + acc[rr][1] * bv.y + acc[rr][2] * bv.z + acc[rr][3] * bv.w;
        ps[rr] += __shfl_xor(ps[rr], 1); ps[rr] += __shfl_xor(ps[rr], 2);
        pd[rr] += __shfl_xor(pd[rr], 1); pd[rr] += __shfl_xor(pd[rr], 2);
    }
    if ((t & 3) == 0) {
        int head = (t & 15) >> 2;
#pragma unroll
        for (int rr = 0; rr < 4; ++rr) {
            int row = row0 + r0 + rr;
            if (row < N) {
                ssrc1[(size_t)row * 4 + head] = ps[rr];
                sdst1[(size_t)row * 4 + head] = pd[rr];
            }
        }
    }
}

// ---------------- Layer 1 softmax-aggregate + fused layer-2 projection ----------------
// TWO nodes per wave (32 lanes each): 4 edge-subsets x 8 channel-octets.
// h1 is fp16: fmaf((float)f16, w, acc) selects v_fma_mix_f32 (no unpack insts).
__device__ __forceinline__ void mix8(float* acc, const uint4& q, float w) {
    f16x2 p0 = __builtin_bit_cast(f16x2, q.x);
    f16x2 p1 = __builtin_bit_cast(f16x2, q.y);
    f16x2 p2 = __builtin_bit_cast(f16x2, q.z);
    f16x2 p3 = __builtin_bit_cast(f16x2, q.w);
    acc[0] = fmaf((float)p0.x, w, acc[0]); acc[1] = fmaf((float)p0.y, w, acc[1]);
    acc[2] = fmaf((float)p1.x, w, acc[2]); acc[3] = fmaf((float)p1.y, w, acc[3]);
    acc[4] = fmaf((float)p2.x, w, acc[4]); acc[5] = fmaf((float)p2.y, w, acc[5]);
    acc[6] = fmaf((float)p3.x, w, acc[6]); acc[7] = fmaf((float)p3.y, w, acc[7]);
}

__global__ __launch_bounds__(256) void agg1_kernel(
    const int2* __restrict__ rng, const int* __restrict__ csr,
    const float* __restrict__ ssrc1, const float* __restrict__ sdst1,
    const uint4* __restrict__ h1q,   // fp16 h1, 8 uint4 per row
    const float* __restrict__ b1, const float* __restrict__ W2,
    const float* __restrict__ a_src2, const float* __restrict__ a_dst2,
    float4* __restrict__ pk2, float* __restrict__ sdst2, int N) {
    const int tid = threadIdx.x;
    const int d = blockIdx.x * 8 + (tid >> 5);
    if (d >= N) return;
    const int l32 = tid & 31;
    const int sub = l32 >> 3;   // edge subset 0..3
    const int chl = l32 & 7;    // channel octet: channels chl*8 .. chl*8+7
    const int h = chl >> 1;     // head of this octet

    const int2 r = rng[d];
    const int beg = r.x;
    const int cnt = r.y - r.x;
    const float bh = sdst1[(size_t)d * 4 + h];

    float acc[8] = {0.f, 0.f, 0.f, 0.f, 0.f, 0.f, 0.f, 0.f};
    float den = 0.f;
    int j = sub;
    for (; j + 4 < cnt; j += 8) {
        int s0 = csr[beg + j];
        int s1 = csr[beg + j + 4];
        float sa0 = ssrc1[(size_t)s0 * 4 + h];
        float sa1 = ssrc1[(size_t)s1 * 4 + h];
        uint4 q0 = h1q[(size_t)s0 * 8 + chl];
        uint4 q1 = h1q[(size_t)s1 * 8 + chl];
        float w0 = __expf(leaky(sa0 + bh));
        float w1 = __expf(leaky(sa1 + bh));
        den += w0 + w1;
        mix8(acc, q0, w0);
        mix8(acc, q1, w1);
    }
    if (j < cnt) {
        int s0 = csr[beg + j];
        float sa0 = ssrc1[(size_t)s0 * 4 + h];
        uint4 q0 = h1q[(size_t)s0 * 8 + chl];
        float w0 = __expf(leaky(sa0 + bh));
        den += w0;
        mix8(acc, q0, w0);
    }
    // Reduce across the 4 edge subsets (lane bits 3,4 — stays within each half-wave).
#pragma unroll
    for (int off = 8; off <= 16; off <<= 1) {
        den += __shfl_xor(den, off);
#pragma unroll
        for (int i = 0; i < 8; ++i) acc[i] += __shfl_xor(acc[i], off);
    }
    if (sub == 0) {
        // In each half-wave, lanes 0..7 hold the full out1 row (8 channels each).
        const float inv = 1.f / den;
        const int c = chl * 8;
        float p0 = 0.f, p1 = 0.f;
#pragma unroll
        for (int i = 0; i < 8; ++i) {
            float e = elu1(acc[i] * inv + b1[c + i]);
            p0 = fmaf(e, W2[(c + i) * 2], p0);
            p1 = fmaf(e, W2[(c + i) * 2 + 1], p1);
        }
        p0 += __shfl_xor(p0, 1); p0 += __shfl_xor(p0, 2); p0 += __shfl_xor(p0, 4);
        p1 += __shfl_xor(p1, 1); p1 += __shfl_xor(p1, 2); p1 += __shfl_xor(p1, 4);
        if (chl == 0) {
            float s2 = p0 * a_src2[0] + p1 * a_src2[1];
            float d2 = p0 * a_dst2[0] + p1 * a_dst2[1];
            pk2[d] = make_float4(p0, p1, s2, 0.f);
            sdst2[d] = d2;
        }
    }
}

// ---------------- Layer 2 softmax-aggregate + log_softmax (2 nodes/wave) ----------------
__global__ __launch_bounds__(256) void agg2_kernel(
    const int2* __restrict__ rng, const int* __restrict__ csr,
    const float4* __restrict__ pk2, const float* __restrict__ sdst2,
    const float* __restrict__ b2, float* __restrict__ out, int N) {
    const int tid = threadIdx.x;
    const int d = blockIdx.x * 8 + (tid >> 5);
    if (d >= N) return;
    const int l32 = tid & 31;
    const int2 r = rng[d];
    const int beg = r.x;
    const int cnt = r.y - r.x;
    const float bs = sdst2[d];

    float den = 0.f, a0 = 0.f, a1 = 0.f;
    int j = l32;
    for (; j + 32 < cnt; j += 64) {
        int s0 = csr[beg + j];
        int s1 = csr[beg + j + 32];
        float4 p0 = pk2[s0];
        float4 p1 = pk2[s1];
        float w0 = __expf(leaky(p0.z + bs));
        float w1 = __expf(leaky(p1.z + bs));
        den += w0 + w1;
        a0 = fmaf(w0, p0.x, a0); a1 = fmaf(w0, p0.y, a1);
        a0 = fmaf(w1, p1.x, a0); a1 = fmaf(w1, p1.y, a1);
    }
    if (j < cnt) {
        int s0 = csr[beg + j];
        float4 p0 = pk2[s0];
        float w0 = __expf(leaky(p0.z + bs));
        den += w0;
        a0 = fmaf(w0, p0.x, a0); a1 = fmaf(w0, p0.y, a1);
    }
#pragma unroll
    for (int off = 1; off <= 16; off <<= 1) {
        den += __shfl_xor(den, off);
        a0  += __shfl_xor(a0, off);
        a1  += __shfl_xor(a1, off);
    }
    if (l32 == 0) {
        float z0 = a0 / den + b2[0];
        float z1 = a1 / den + b2[1];
        float mx = fmaxf(z0, z1);
        float lse = mx + logf(__expf(z0 - mx) + __expf(z1 - mx));
        *(float2*)&out[(size_t)d * 2] = make_float2(z0 - lse, z1 - lse);
    }
}

extern "C" void kernel_launch(void* const* d_in, const int* in_sizes, int n_in,
                              void* d_out, int out_size, void* d_ws, size_t ws_size,
                              hipStream_t stream) {
    const float* x   = (const float*)d_in[0];
    const int*   ei  = (const int*)d_in[1];
    const float* W1  = (const float*)d_in[2];
    const float* as1 = (const float*)d_in[3];
    const float* ad1 = (const float*)d_in[4];
    const float* b1  = (const float*)d_in[5];
    const float* W2  = (const float*)d_in[6];
    const float* as2 = (const float*)d_in[7];
    const float* ad2 = (const float*)d_in[8];
    const float* b2  = (const float*)d_in[9];

    const int N    = in_sizes[0] / 128;
    const int E    = in_sizes[1] / 2;
    const int Etot = E + N;
    const int NB   = (N + 63) >> 6;   // 64-node buckets
    const int* src = ei;
    const int* dst = ei + E;

    char* p = (char*)d_ws;
    float4* pk2 = (float4*)p;           p += (size_t)N * 16;
    unsigned short* h1b = (unsigned short*)p; p += (size_t)N * 64 * 2;
    float* ssrc1 = (float*)p;           p += (size_t)N * 4 * 4;
    float* sdst1 = (float*)p;           p += (size_t)N * 4 * 4;
    float* sdst2 = (float*)p;           p += (size_t)N * 4;
    int2* rng    = (int2*)p;            p += (size_t)N * 8;
    int* cursor  = (int*)p;             p += 1024 * 4;
    unsigned* binned = (unsigned*)p;    p += (size_t)NB * CAP * 4;
    int* csr     = (int*)p;             p += (size_t)NB * CAP * 4;

    hipMemsetAsync(cursor, 0, 1024 * sizeof(int), stream);

    const int nbin = (Etot + BIN_CHUNK - 1) / BIN_CHUNK;
    bin_kernel<<<nbin, 256, 0, stream>>>(src, dst, cursor, binned, E, Etot, NB);
    csr_build_kernel<<<NB, 256, 0, stream>>>(binned, cursor, rng, csr, N, NB);
    gemm1_kernel<<<(N + 63) / 64, 256, 0, stream>>>(x, W1, as1, ad1, h1b, ssrc1, sdst1, N);
    agg1_kernel<<<(N + 7) / 8, 256, 0, stream>>>(rng, csr, ssrc1, sdst1,
                                                 (const uint4*)h1b, b1, W2, as2, ad2,
                                                 pk2, sdst2, N);
    agg2_kernel<<<(N + 7) / 8, 256, 0, stream>>>(rng, csr, pk2, sdst2, b2,
                                                 (float*)d_out, N);
}

// Round 10
// 196.107 us; speedup vs baseline: 1.0166x; 1.0166x over previous
//
#include <hip/hip_runtime.h>
#include <cstdint>
#include <cstddef>

// GAT 2-layer forward. Bucket bin (64-node buckets) -> exact CSR,
// fused softmax-aggregate (2 nodes/wave) with gemm2 in agg1 epilogue,
// h1 stored FP16 (v_fma_mix), agg1 gather loop 4-deep unrolled for MLP.

#define NEG_SLOPE 0.2f
#define BIN_CHUNK 4096
#define CAP 2560   // per-bucket slice capacity; mean count ~2112 (9.7 sigma)

typedef _Float16 f16x2 __attribute__((ext_vector_type(2)));

__device__ __forceinline__ float leaky(float v) {
    return v >= 0.f ? v : NEG_SLOPE * v;
}
__device__ __forceinline__ float elu1(float v) {
    return v > 0.f ? v : expm1f(v);
}

// ---------------- K1: bin edges into fixed-capacity bucket slices ----------------
__global__ __launch_bounds__(256) void bin_kernel(
    const int* __restrict__ src, const int* __restrict__ dst,
    int* __restrict__ cursor, unsigned* __restrict__ binned,
    int E, int Etot, int NB) {
    __shared__ int hist[800];
    __shared__ int basesh[800];
    for (int i = threadIdx.x; i < NB; i += 256) hist[i] = 0;
    __syncthreads();
    unsigned pk[BIN_CHUNK / 256];
    int base = blockIdx.x * BIN_CHUNK;
#pragma unroll
    for (int k = 0; k < BIN_CHUNK / 256; ++k) {
        int e = base + k * 256 + threadIdx.x;
        pk[k] = 0xFFFFFFFFu;
        if (e < Etot) {
            int s, d;
            if (e < E) { s = src[e]; d = dst[e]; }
            else       { s = d = e - E; }  // self loops appended
            pk[k] = ((unsigned)d << 16) | (unsigned)s;
            atomicAdd(&hist[d >> 6], 1);
        }
    }
    __syncthreads();
    for (int i = threadIdx.x; i < NB; i += 256) {
        int c = hist[i];
        basesh[i] = c ? (i * CAP + atomicAdd(&cursor[i], c)) : 0;
        hist[i] = 0;  // reuse as local cursor
    }
    __syncthreads();
#pragma unroll
    for (int k = 0; k < BIN_CHUNK / 256; ++k) {
        if (pk[k] != 0xFFFFFFFFu) {
            int b = pk[k] >> 22;  // = dst >> 6
            int pos = basesh[b] + atomicAdd(&hist[b], 1);
            binned[pos] = pk[k];
        }
    }
}

// ---------------- K2: per-bucket (64 nodes) exact CSR ----------------
__global__ __launch_bounds__(256) void csr_build_kernel(
    const unsigned* __restrict__ binned, const int* __restrict__ cursor,
    int2* __restrict__ rng, int* __restrict__ csr, int N, int NB) {
    __shared__ int hist[64];
    __shared__ int sc[64];
    __shared__ int cur[64];
    const int b = blockIdx.x;
    const int base = b * CAP;
    const int endp = base + cursor[b];
    const int t = threadIdx.x;
    if (t < 64) hist[t] = 0;
    __syncthreads();
    for (int i = base + t; i < endp; i += 256)
        atomicAdd(&hist[(binned[i] >> 16) & 63], 1);
    __syncthreads();
    int v = (t < 64) ? hist[t] : 0;
    if (t < 64) sc[t] = v;
    __syncthreads();
    for (int off = 1; off < 64; off <<= 1) {
        int u = (t >= off && t < 64) ? sc[t - off] : 0;
        __syncthreads();
        if (t < 64) sc[t] += u;
        __syncthreads();
    }
    if (t < 64) {
        int beg = base + sc[t] - v;
        cur[t] = beg;
        int node = b * 64 + t;
        if (node < N) rng[node] = make_int2(beg, beg + v);
    }
    __syncthreads();
    for (int i = base + t; i < endp; i += 256) {
        unsigned p = binned[i];
        int pos = atomicAdd(&cur[(p >> 16) & 63], 1);
        csr[pos] = (int)(p & 0xFFFFu);
    }
}

// ---------------- Layer 1 GEMM (x @ W1) + scores, fp16 h1 out ----------------
__global__ __launch_bounds__(256) void gemm1_kernel(
    const float* __restrict__ x, const float* __restrict__ W1,
    const float* __restrict__ a_src, const float* __restrict__ a_dst,
    unsigned short* __restrict__ h1b, float* __restrict__ ssrc1,
    float* __restrict__ sdst1, int N) {
    __shared__ float Ws[128 * 64];
    __shared__ float Xt[128][69];

    const int t = threadIdx.x;
    const int row0 = blockIdx.x * 64;

    for (int i = t * 4; i < 128 * 64; i += 1024) {
        *(float4*)&Ws[i] = *(const float4*)&W1[i];
    }
    for (int i = t * 4; i < 64 * 128; i += 1024) {
        int r = i >> 7, k = i & 127;
        float4 v = make_float4(0.f, 0.f, 0.f, 0.f);
        if (row0 + r < N) v = *(const float4*)&x[(size_t)(row0 + r) * 128 + k];
        Xt[k][r] = v.x; Xt[k + 1][r] = v.y; Xt[k + 2][r] = v.z; Xt[k + 3][r] = v.w;
    }
    __syncthreads();

    const int r0 = (t >> 4) * 4;
    const int c0 = (t & 15) * 4;
    float acc[4][4] = {};
#pragma unroll 4
    for (int k = 0; k < 128; ++k) {
        float4 wv = *(const float4*)&Ws[k * 64 + c0];
        float4 xv = *(const float4*)&Xt[k][r0];
        acc[0][0] = fmaf(xv.x, wv.x, acc[0][0]); acc[0][1] = fmaf(xv.x, wv.y, acc[0][1]);
        acc[0][2] = fmaf(xv.x, wv.z, acc[0][2]); acc[0][3] = fmaf(xv.x, wv.w, acc[0][3]);
        acc[1][0] = fmaf(xv.y, wv.x, acc[1][0]); acc[1][1] = fmaf(xv.y, wv.y, acc[1][1]);
        acc[1][2] = fmaf(xv.y, wv.z, acc[1][2]); acc[1][3] = fmaf(xv.y, wv.w, acc[1][3]);
        acc[2][0] = fmaf(xv.z, wv.x, acc[2][0]); acc[2][1] = fmaf(xv.z, wv.y, acc[2][1]);
        acc[2][2] = fmaf(xv.z, wv.z, acc[2][2]); acc[2][3] = fmaf(xv.z, wv.w, acc[2][3]);
        acc[3][0] = fmaf(xv.w, wv.x, acc[3][0]); acc[3][1] = fmaf(xv.w, wv.y, acc[3][1]);
        acc[3][2] = fmaf(xv.w, wv.z, acc[3][2]); acc[3][3] = fmaf(xv.w, wv.w, acc[3][3]);
    }
    float4 av = *(const float4*)&a_src[c0];
    float4 bv = *(const float4*)&a_dst[c0];
    float ps[4], pd[4];
#pragma unroll
    for (int rr = 0; rr < 4; ++rr) {
        int row = row0 + r0 + rr;
        if (row < N) {
            f16x2 u0 = {(_Float16)acc[rr][0], (_Float16)acc[rr][1]};
            f16x2 u1 = {(_Float16)acc[rr][2], (_Float16)acc[rr][3]};
            uint2 st;
            st.x = __builtin_bit_cast(unsigned, u0);
            st.y = __builtin_bit_cast(unsigned, u1);
            *(uint2*)&h1b[(size_t)row * 64 + c0] = st;
        }
        ps[rr] = acc[rr][0] * av.x + acc[rr][1] * av.y + acc[rr][2] * av.z + acc[rr][3] * av.w;
        pd[rr] = acc[rr][0] * bv.x + acc[rr][1] * bv.y + acc[rr][2] * bv.z + acc[rr][3] * bv.w;
        ps[rr] += __shfl_xor(ps[rr], 1); ps[rr] += __shfl_xor(ps[rr], 2);
        pd[rr] += __shfl_xor(pd[rr], 1); pd[rr] += __shfl_xor(pd[rr], 2);
    }
    if ((t & 3) == 0) {
        int head = (t & 15) >> 2;
#pragma unroll
        for (int rr = 0; rr < 4; ++rr) {
            int row = row0 + r0 + rr;
            if (row < N) {
                ssrc1[(size_t)row * 4 + head] = ps[rr];
                sdst1[(size_t)row * 4 + head] = pd[rr];
            }
        }
    }
}

// ---------------- Layer 1 softmax-aggregate + fused layer-2 projection ----------------
// TWO nodes per wave (32 lanes each): 4 edge-subsets x 8 channel-octets.
// 4-deep unroll: 4 independent csr->ssrc/h1 gather chains in flight per subset.
__device__ __forceinline__ void mix8(float* acc, const uint4& q, float w) {
    f16x2 p0 = __builtin_bit_cast(f16x2, q.x);
    f16x2 p1 = __builtin_bit_cast(f16x2, q.y);
    f16x2 p2 = __builtin_bit_cast(f16x2, q.z);
    f16x2 p3 = __builtin_bit_cast(f16x2, q.w);
    acc[0] = fmaf((float)p0.x, w, acc[0]); acc[1] = fmaf((float)p0.y, w, acc[1]);
    acc[2] = fmaf((float)p1.x, w, acc[2]); acc[3] = fmaf((float)p1.y, w, acc[3]);
    acc[4] = fmaf((float)p2.x, w, acc[4]); acc[5] = fmaf((float)p2.y, w, acc[5]);
    acc[6] = fmaf((float)p3.x, w, acc[6]); acc[7] = fmaf((float)p3.y, w, acc[7]);
}

__global__ __launch_bounds__(256) void agg1_kernel(
    const int2* __restrict__ rng, const int* __restrict__ csr,
    const float* __restrict__ ssrc1, const float* __restrict__ sdst1,
    const uint4* __restrict__ h1q,   // fp16 h1, 8 uint4 per row
    const float* __restrict__ b1, const float* __restrict__ W2,
    const float* __restrict__ a_src2, const float* __restrict__ a_dst2,
    float4* __restrict__ pk2, float* __restrict__ sdst2, int N) {
    const int tid = threadIdx.x;
    const int d = blockIdx.x * 8 + (tid >> 5);
    if (d >= N) return;
    const int l32 = tid & 31;
    const int sub = l32 >> 3;   // edge subset 0..3
    const int chl = l32 & 7;    // channel octet
    const int h = chl >> 1;     // head of this octet

    const int2 r = rng[d];
    const int beg = r.x;
    const int cnt = r.y - r.x;
    const float bh = sdst1[(size_t)d * 4 + h];

    float acc[8] = {0.f, 0.f, 0.f, 0.f, 0.f, 0.f, 0.f, 0.f};
    float den = 0.f;
    int j = sub;
    for (; j + 12 < cnt; j += 16) {
        int s0 = csr[beg + j];
        int s1 = csr[beg + j + 4];
        int s2 = csr[beg + j + 8];
        int s3 = csr[beg + j + 12];
        float sa0 = ssrc1[(size_t)s0 * 4 + h];
        float sa1 = ssrc1[(size_t)s1 * 4 + h];
        float sa2 = ssrc1[(size_t)s2 * 4 + h];
        float sa3 = ssrc1[(size_t)s3 * 4 + h];
        uint4 q0 = h1q[(size_t)s0 * 8 + chl];
        uint4 q1 = h1q[(size_t)s1 * 8 + chl];
        uint4 q2 = h1q[(size_t)s2 * 8 + chl];
        uint4 q3 = h1q[(size_t)s3 * 8 + chl];
        float w0 = __expf(leaky(sa0 + bh));
        float w1 = __expf(leaky(sa1 + bh));
        float w2 = __expf(leaky(sa2 + bh));
        float w3 = __expf(leaky(sa3 + bh));
        den += (w0 + w1) + (w2 + w3);
        mix8(acc, q0, w0);
        mix8(acc, q1, w1);
        mix8(acc, q2, w2);
        mix8(acc, q3, w3);
    }
    for (; j < cnt; j += 4) {
        int s0 = csr[beg + j];
        float sa0 = ssrc1[(size_t)s0 * 4 + h];
        uint4 q0 = h1q[(size_t)s0 * 8 + chl];
        float w0 = __expf(leaky(sa0 + bh));
        den += w0;
        mix8(acc, q0, w0);
    }
    // Reduce across the 4 edge subsets (lane bits 3,4 — within each half-wave).
#pragma unroll
    for (int off = 8; off <= 16; off <<= 1) {
        den += __shfl_xor(den, off);
#pragma unroll
        for (int i = 0; i < 8; ++i) acc[i] += __shfl_xor(acc[i], off);
    }
    if (sub == 0) {
        const float inv = 1.f / den;
        const int c = chl * 8;
        float p0 = 0.f, p1 = 0.f;
#pragma unroll
        for (int i = 0; i < 8; ++i) {
            float e = elu1(acc[i] * inv + b1[c + i]);
            p0 = fmaf(e, W2[(c + i) * 2], p0);
            p1 = fmaf(e, W2[(c + i) * 2 + 1], p1);
        }
        p0 += __shfl_xor(p0, 1); p0 += __shfl_xor(p0, 2); p0 += __shfl_xor(p0, 4);
        p1 += __shfl_xor(p1, 1); p1 += __shfl_xor(p1, 2); p1 += __shfl_xor(p1, 4);
        if (chl == 0) {
            float s2 = p0 * a_src2[0] + p1 * a_src2[1];
            float d2 = p0 * a_dst2[0] + p1 * a_dst2[1];
            pk2[d] = make_float4(p0, p1, s2, 0.f);
            sdst2[d] = d2;
        }
    }
}

// ---------------- Layer 2 softmax-aggregate + log_softmax (2 nodes/wave) ----------------
__global__ __launch_bounds__(256) void agg2_kernel(
    const int2* __restrict__ rng, const int* __restrict__ csr,
    const float4* __restrict__ pk2, const float* __restrict__ sdst2,
    const float* __restrict__ b2, float* __restrict__ out, int N) {
    const int tid = threadIdx.x;
    const int d = blockIdx.x * 8 + (tid >> 5);
    if (d >= N) return;
    const int l32 = tid & 31;
    const int2 r = rng[d];
    const int beg = r.x;
    const int cnt = r.y - r.x;
    const float bs = sdst2[d];

    float den = 0.f, a0 = 0.f, a1 = 0.f;
    int j = l32;
    for (; j + 32 < cnt; j += 64) {
        int s0 = csr[beg + j];
        int s1 = csr[beg + j + 32];
        float4 p0 = pk2[s0];
        float4 p1 = pk2[s1];
        float w0 = __expf(leaky(p0.z + bs));
        float w1 = __expf(leaky(p1.z + bs));
        den += w0 + w1;
        a0 = fmaf(w0, p0.x, a0); a1 = fmaf(w0, p0.y, a1);
        a0 = fmaf(w1, p1.x, a0); a1 = fmaf(w1, p1.y, a1);
    }
    if (j < cnt) {
        int s0 = csr[beg + j];
        float4 p0 = pk2[s0];
        float w0 = __expf(leaky(p0.z + bs));
        den += w0;
        a0 = fmaf(w0, p0.x, a0); a1 = fmaf(w0, p0.y, a1);
    }
#pragma unroll
    for (int off = 1; off <= 16; off <<= 1) {
        den += __shfl_xor(den, off);
        a0  += __shfl_xor(a0, off);
        a1  += __shfl_xor(a1, off);
    }
    if (l32 == 0) {
        float z0 = a0 / den + b2[0];
        float z1 = a1 / den + b2[1];
        float mx = fmaxf(z0, z1);
        float lse = mx + logf(__expf(z0 - mx) + __expf(z1 - mx));
        *(float2*)&out[(size_t)d * 2] = make_float2(z0 - lse, z1 - lse);
    }
}

extern "C" void kernel_launch(void* const* d_in, const int* in_sizes, int n_in,
                              void* d_out, int out_size, void* d_ws, size_t ws_size,
                              hipStream_t stream) {
    const float* x   = (const float*)d_in[0];
    const int*   ei  = (const int*)d_in[1];
    const float* W1  = (const float*)d_in[2];
    const float* as1 = (const float*)d_in[3];
    const float* ad1 = (const float*)d_in[4];
    const float* b1  = (const float*)d_in[5];
    const float* W2  = (const float*)d_in[6];
    const float* as2 = (const float*)d_in[7];
    const float* ad2 = (const float*)d_in[8];
    const float* b2  = (const float*)d_in[9];

    const int N    = in_sizes[0] / 128;
    const int E    = in_sizes[1] / 2;
    const int Etot = E + N;
    const int NB   = (N + 63) >> 6;   // 64-node buckets
    const int* src = ei;
    const int* dst = ei + E;

    char* p = (char*)d_ws;
    float4* pk2 = (float4*)p;           p += (size_t)N * 16;
    unsigned short* h1b = (unsigned short*)p; p += (size_t)N * 64 * 2;
    float* ssrc1 = (float*)p;           p += (size_t)N * 4 * 4;
    float* sdst1 = (float*)p;           p += (size_t)N * 4 * 4;
    float* sdst2 = (float*)p;           p += (size_t)N * 4;
    int2* rng    = (int2*)p;            p += (size_t)N * 8;
    int* cursor  = (int*)p;             p += 1024 * 4;
    unsigned* binned = (unsigned*)p;    p += (size_t)NB * CAP * 4;
    int* csr     = (int*)p;             p += (size_t)NB * CAP * 4;

    hipMemsetAsync(cursor, 0, 1024 * sizeof(int), stream);

    const int nbin = (Etot + BIN_CHUNK - 1) / BIN_CHUNK;
    bin_kernel<<<nbin, 256, 0, stream>>>(src, dst, cursor, binned, E, Etot, NB);
    csr_build_kernel<<<NB, 256, 0, stream>>>(binned, cursor, rng, csr, N, NB);
    gemm1_kernel<<<(N + 63) / 64, 256, 0, stream>>>(x, W1, as1, ad1, h1b, ssrc1, sdst1, N);
    agg1_kernel<<<(N + 7) / 8, 256, 0, stream>>>(rng, csr, ssrc1, sdst1,
                                                 (const uint4*)h1b, b1, W2, as2, ad2,
                                                 pk2, sdst2, N);
    agg2_kernel<<<(N + 7) / 8, 256, 0, stream>>>(rng, csr, pk2, sdst2, b2,
                                                 (float*)d_out, N);
}